// Round 1
// baseline (298.715 us; speedup 1.0000x reference)
//
#include <hip/hip_runtime.h>
#include <math.h>

#define N_CLS 1000
#define FEAT  1024
#define BATCH 32768
#define NBLK_H 128
#define CHUNK  256

// ---------------- counting-sort: histogram ----------------
__global__ __launch_bounds__(256) void hist_kernel(const int* __restrict__ labels,
                                                   unsigned* __restrict__ hist) {
    __shared__ unsigned cnt[N_CLS];
    const int t = threadIdx.x, b = blockIdx.x;
    for (int i = t; i < N_CLS; i += 256) cnt[i] = 0;
    __syncthreads();
    const int l = labels[b * CHUNK + t];
    atomicAdd(&cnt[l], 1u);
    __syncthreads();
    for (int i = t; i < N_CLS; i += 256) hist[(size_t)b * N_CLS + i] = cnt[i];
}

// ---------------- counting-sort: offsets (single block) ----------------
__global__ __launch_bounds__(1024) void offsets_kernel(unsigned* __restrict__ hist,
                                                       unsigned* __restrict__ base,
                                                       unsigned* __restrict__ total) {
    const int t = threadIdx.x;
    unsigned run = 0;
    if (t < N_CLS) {
        for (int b = 0; b < NBLK_H; ++b) {
            unsigned v = hist[(size_t)b * N_CLS + t];
            hist[(size_t)b * N_CLS + t] = run;   // per-label prefix over blocks
            run += v;
        }
        total[t] = run;
    }
    __shared__ unsigned sc[1024];
    sc[t] = (t < N_CLS) ? run : 0u;
    __syncthreads();
    for (int off = 1; off < 1024; off <<= 1) {
        unsigned v = sc[t];
        unsigned u = (t >= off) ? sc[t - off] : 0u;
        __syncthreads();
        sc[t] = v + u;
        __syncthreads();
    }
    if (t < N_CLS) base[t] = sc[t] - run;        // exclusive prefix
}

// ---------------- counting-sort: stable scatter ----------------
__global__ __launch_bounds__(256) void scatter_kernel(const int* __restrict__ labels,
                                                      const unsigned* __restrict__ hist,
                                                      const unsigned* __restrict__ base,
                                                      int* __restrict__ sorted_idx) {
    __shared__ int lbl[CHUNK];
    const int t = threadIdx.x, b = blockIdx.x;
    const int i = b * CHUNK + t;
    const int l = labels[i];
    lbl[t] = l;
    __syncthreads();
    int rank = 0;
    for (int j = 0; j < t; ++j) rank += (lbl[j] == l);
    const unsigned pos = base[l] + hist[(size_t)b * N_CLS + l] + (unsigned)rank;
    sorted_idx[pos] = i;
}

// ---------------- EMA chains: one wave per label ----------------
__device__ __forceinline__ float4 ema4(float4 p, float4 f) {
    p.x = fmaf(0.95f, p.x, 0.05f * f.x);
    p.y = fmaf(0.95f, p.y, 0.05f * f.y);
    p.z = fmaf(0.95f, p.z, 0.05f * f.z);
    p.w = fmaf(0.95f, p.w, 0.05f * f.w);
    return p;
}
__device__ __forceinline__ float dot4(float4 a) {
    return a.x * a.x + a.y * a.y + a.z * a.z + a.w * a.w;
}
__device__ __forceinline__ float4 scale4(float4 a, float s) {
    a.x *= s; a.y *= s; a.z *= s; a.w *= s; return a;
}

__global__ __launch_bounds__(256) void ema_kernel(const float* __restrict__ features,
                                                  const float* __restrict__ prototypes,
                                                  const int* __restrict__ sorted_idx,
                                                  const unsigned* __restrict__ base,
                                                  const unsigned* __restrict__ total,
                                                  float* __restrict__ protos_new) {
    const int w    = blockIdx.x * 4 + (threadIdx.x >> 6);   // label, 0..999
    const int lane = threadIdx.x & 63;
    const float4* pr = (const float4*)(prototypes + (size_t)w * FEAT);
    float4 p0 = pr[lane], p1 = pr[lane + 64], p2 = pr[lane + 128], p3 = pr[lane + 192];

    const int cnt = (int)total[w];
    const int bs  = (int)base[w];
    int sidx = (cnt > 0) ? sorted_idx[bs] : 0;
    for (int k = 0; k < cnt; ++k) {
        const float4* fr = (const float4*)(features + (size_t)sidx * FEAT);
        float4 f0 = fr[lane], f1 = fr[lane + 64], f2 = fr[lane + 128], f3 = fr[lane + 192];
        int nidx = (k + 1 < cnt) ? sorted_idx[bs + k + 1] : 0;   // prefetch index
        p0 = ema4(p0, f0); p1 = ema4(p1, f1); p2 = ema4(p2, f2); p3 = ema4(p3, f3);
        float ss = dot4(p0) + dot4(p1) + dot4(p2) + dot4(p3);
        #pragma unroll
        for (int off = 32; off; off >>= 1) ss += __shfl_xor(ss, off, 64);
        const float inv = 1.0f / fmaxf(sqrtf(ss), 1e-12f);
        p0 = scale4(p0, inv); p1 = scale4(p1, inv); p2 = scale4(p2, inv); p3 = scale4(p3, inv);
        sidx = nidx;
    }
    float4* out = (float4*)(protos_new + (size_t)w * FEAT);
    out[lane] = p0; out[lane + 64] = p1; out[lane + 128] = p2; out[lane + 192] = p3;
}

// ---------------- Gram + exp row-sums ----------------
#define BM 64
#define BN 32
#define BK 32

__global__ __launch_bounds__(256) void gram_kernel(const float* __restrict__ P,
                                                   float* __restrict__ S) {
    __shared__ float As[BK][BM + 2];   // k-major, stride 66 (even, 2-way max)
    __shared__ float Bs[BK][BN + 4];   // k-major, stride 36 (16B-aligned cols)
    const int t  = threadIdx.x;
    const int bx = blockIdx.x;         // col tile (32 tiles)
    const int by = blockIdx.y;         // row tile (16 tiles)
    const int tc = t & 7;              // 0..7 -> c0 = tc*4
    const int tr = t >> 3;             // 0..31 -> r0 = tr*2
    const int c0 = tc * 4, r0 = tr * 2;

    float acc[2][4] = {{0.f,0.f,0.f,0.f},{0.f,0.f,0.f,0.f}};

    const int la_r = t >> 3;           // 0..31 (rows la_r and la_r+32)
    const int la_k = (t & 7) * 4;

    for (int k0 = 0; k0 < FEAT; k0 += BK) {
        #pragma unroll
        for (int h = 0; h < 2; ++h) {
            const int r  = la_r + h * 32;
            const int gr = by * BM + r;
            float4 v = make_float4(0.f, 0.f, 0.f, 0.f);
            if (gr < N_CLS) v = *(const float4*)(P + (size_t)gr * FEAT + k0 + la_k);
            As[la_k + 0][r] = v.x; As[la_k + 1][r] = v.y;
            As[la_k + 2][r] = v.z; As[la_k + 3][r] = v.w;
        }
        {
            const int gc = bx * BN + la_r;
            float4 v = make_float4(0.f, 0.f, 0.f, 0.f);
            if (gc < N_CLS) v = *(const float4*)(P + (size_t)gc * FEAT + k0 + la_k);
            Bs[la_k + 0][la_r] = v.x; Bs[la_k + 1][la_r] = v.y;
            Bs[la_k + 2][la_r] = v.z; Bs[la_k + 3][la_r] = v.w;
        }
        __syncthreads();
        #pragma unroll
        for (int k = 0; k < BK; ++k) {
            const float a0 = As[k][r0], a1 = As[k][r0 + 1];
            const float b0 = Bs[k][c0], b1 = Bs[k][c0 + 1];
            const float b2 = Bs[k][c0 + 2], b3 = Bs[k][c0 + 3];
            acc[0][0] = fmaf(a0, b0, acc[0][0]); acc[0][1] = fmaf(a0, b1, acc[0][1]);
            acc[0][2] = fmaf(a0, b2, acc[0][2]); acc[0][3] = fmaf(a0, b3, acc[0][3]);
            acc[1][0] = fmaf(a1, b0, acc[1][0]); acc[1][1] = fmaf(a1, b1, acc[1][1]);
            acc[1][2] = fmaf(a1, b2, acc[1][2]); acc[1][3] = fmaf(a1, b3, acc[1][3]);
        }
        __syncthreads();
    }

    // exp row-sums (exclude diagonal and out-of-range), reduce over the 8 lanes of tc
    float rs[2];
    #pragma unroll
    for (int i = 0; i < 2; ++i) {
        const int gr = by * BM + r0 + i;
        float s = 0.f;
        #pragma unroll
        for (int j = 0; j < 4; ++j) {
            const int gc = bx * BN + c0 + j;
            if (gr < N_CLS && gc < N_CLS && gr != gc) s += expf(acc[i][j] * 10.0f);
        }
        rs[i] = s;
    }
    #pragma unroll
    for (int m = 1; m < 8; m <<= 1) {
        rs[0] += __shfl_xor(rs[0], m, 64);
        rs[1] += __shfl_xor(rs[1], m, 64);
    }
    if (tc == 0) {
        #pragma unroll
        for (int i = 0; i < 2; ++i) {
            const int gr = by * BM + r0 + i;
            if (gr < N_CLS) atomicAdd(&S[gr], rs[i]);
        }
    }
}

// ---------------- final loss ----------------
__global__ __launch_bounds__(1024) void loss_kernel(const float* __restrict__ S,
                                                    float* __restrict__ out) {
    const int t = threadIdx.x;
    float v = 0.f;
    if (t < N_CLS) v = logf(S[t]) - logf(999.0f);
    #pragma unroll
    for (int off = 32; off; off >>= 1) v += __shfl_xor(v, off, 64);
    __shared__ float red[16];
    const int wv = t >> 6, lane = t & 63;
    if (lane == 0) red[wv] = v;
    __syncthreads();
    if (t < 16) {
        float s = red[t];
        #pragma unroll
        for (int off = 8; off; off >>= 1) s += __shfl_xor(s, off, 16);
        if (t == 0) out[0] = s / (float)N_CLS;   // TEMP/BASE_TEMP == 1.0
    }
}

extern "C" void kernel_launch(void* const* d_in, const int* in_sizes, int n_in,
                              void* d_out, int out_size, void* d_ws, size_t ws_size,
                              hipStream_t stream) {
    const float* features   = (const float*)d_in[0];
    const float* prototypes = (const float*)d_in[1];
    const int*   labels     = (const int*)d_in[2];
    float* out = (float*)d_out;

    char* ws = (char*)d_ws;
    unsigned* hist   = (unsigned*)(ws);                       // 128*1000*4 = 512000
    unsigned* base   = (unsigned*)(ws + 512000);              // 4096
    unsigned* total  = (unsigned*)(ws + 516096);              // 4096
    int*      sorted = (int*)     (ws + 520192);              // 32768*4 = 131072
    float*    pnew   = (float*)   (ws + 651264);              // 1000*1024*4 = 4096000
    float*    S      = (float*)   (ws + 651264 + 4096000);    // 1000*4

    hist_kernel   <<<NBLK_H, 256, 0, stream>>>(labels, hist);
    offsets_kernel<<<1, 1024, 0, stream>>>(hist, base, total);
    scatter_kernel<<<NBLK_H, 256, 0, stream>>>(labels, hist, base, sorted);
    ema_kernel    <<<250, 256, 0, stream>>>(features, prototypes, sorted, base, total, pnew);
    hipMemsetAsync(S, 0, N_CLS * sizeof(float), stream);
    gram_kernel   <<<dim3(32, 16), 256, 0, stream>>>(pnew, S);
    loss_kernel   <<<1, 1024, 0, stream>>>(S, out);
}

// Round 2
// 265.435 us; speedup vs baseline: 1.1254x; 1.1254x over previous
//
#include <hip/hip_runtime.h>
#include <hip/hip_bf16.h>
#include <math.h>

#define N_CLS 1000
#define FEAT  1024
#define BATCH 32768
#define NBLK_H 128
#define CHUNK  256
#define KCAT   3072
#define GBK    64
#define LPITCH 72

typedef short short8 __attribute__((ext_vector_type(8)));
typedef float f32x4  __attribute__((ext_vector_type(4)));

__device__ __forceinline__ unsigned short f2bf(float x) {
    union { __hip_bfloat16 h; unsigned short u; } cv;
    cv.h = __float2bfloat16(x);
    return cv.u;
}
__device__ __forceinline__ float bf2f(unsigned short u) {
    union { __hip_bfloat16 h; unsigned short u; } cv;
    cv.u = u;
    return __bfloat162float(cv.h);
}

// ---------------- counting-sort: histogram (transposed layout hist[l][b]) ----------------
__global__ __launch_bounds__(256) void hist_kernel(const int* __restrict__ labels,
                                                   unsigned* __restrict__ hist) {
    __shared__ unsigned cnt[N_CLS];
    const int t = threadIdx.x, b = blockIdx.x;
    for (int i = t; i < N_CLS; i += 256) cnt[i] = 0;
    __syncthreads();
    atomicAdd(&cnt[labels[b * CHUNK + t]], 1u);
    __syncthreads();
    for (int i = t; i < N_CLS; i += 256) hist[(size_t)i * NBLK_H + b] = cnt[i];
}

// ---------------- per-label wave scan over the 128 blocks ----------------
__global__ __launch_bounds__(256) void scan1_kernel(unsigned* __restrict__ hist,
                                                    unsigned* __restrict__ total) {
    const int l    = blockIdx.x * 4 + (threadIdx.x >> 6);
    const int lane = threadIdx.x & 63;
    unsigned v0 = hist[(size_t)l * NBLK_H + lane];
    unsigned v1 = hist[(size_t)l * NBLK_H + 64 + lane];
    unsigned x0 = v0, x1 = v1;
    #pragma unroll
    for (int off = 1; off < 64; off <<= 1) {
        unsigned u0 = __shfl_up(x0, off, 64);
        if (lane >= off) x0 += u0;
        unsigned u1 = __shfl_up(x1, off, 64);
        if (lane >= off) x1 += u1;
    }
    x1 += __shfl(x0, 63, 64);
    hist[(size_t)l * NBLK_H + lane]      = x0 - v0;   // exclusive prefix
    hist[(size_t)l * NBLK_H + 64 + lane] = x1 - v1;
    if (lane == 63) total[l] = x1;
}

// ---------------- exclusive scan of per-label totals ----------------
__global__ __launch_bounds__(1024) void scan2_kernel(const unsigned* __restrict__ total,
                                                     unsigned* __restrict__ base) {
    const int t = threadIdx.x;
    unsigned v = (t < N_CLS) ? total[t] : 0u;
    __shared__ unsigned sc[1024];
    sc[t] = v;
    __syncthreads();
    for (int off = 1; off < 1024; off <<= 1) {
        unsigned u = (t >= off) ? sc[t - off] : 0u;
        __syncthreads();
        sc[t] += u;
        __syncthreads();
    }
    if (t < N_CLS) base[t] = sc[t] - v;
}

// ---------------- counting-sort: stable scatter ----------------
__global__ __launch_bounds__(256) void scatter_kernel(const int* __restrict__ labels,
                                                      const unsigned* __restrict__ hist,
                                                      const unsigned* __restrict__ base,
                                                      int* __restrict__ sorted_idx) {
    __shared__ int lbl[CHUNK];
    __shared__ unsigned c[N_CLS];
    const int t = threadIdx.x, b = blockIdx.x;
    for (int i = t; i < N_CLS; i += 256) c[i] = 0;
    __syncthreads();
    const int i = b * CHUNK + t;
    const int l = labels[i];
    lbl[t] = l;
    atomicAdd(&c[l], 1u);
    __syncthreads();
    int rank = 0;
    if (c[l] > 1) {                       // only duplicated-in-block labels need ranking
        for (int j = 0; j < t; ++j) rank += (lbl[j] == l);
    }
    sorted_idx[base[l] + hist[(size_t)l * NBLK_H + b] + (unsigned)rank] = i;
}

// ---------------- EMA chains: one wave per label, 2-deep data prefetch ----------------
__device__ __forceinline__ float4 ema4(float4 p, float4 f) {
    p.x = fmaf(0.95f, p.x, 0.05f * f.x);
    p.y = fmaf(0.95f, p.y, 0.05f * f.y);
    p.z = fmaf(0.95f, p.z, 0.05f * f.z);
    p.w = fmaf(0.95f, p.w, 0.05f * f.w);
    return p;
}
__device__ __forceinline__ float dot4(float4 a) {
    return a.x * a.x + a.y * a.y + a.z * a.z + a.w * a.w;
}
__device__ __forceinline__ float4 scale4(float4 a, float s) {
    a.x *= s; a.y *= s; a.z *= s; a.w *= s; return a;
}

__global__ __launch_bounds__(256) void ema_kernel(const float* __restrict__ features,
                                                  const float* __restrict__ prototypes,
                                                  const int* __restrict__ sorted_idx,
                                                  const unsigned* __restrict__ base,
                                                  const unsigned* __restrict__ total,
                                                  float* __restrict__ protos_new) {
    const int w    = blockIdx.x * 4 + (threadIdx.x >> 6);
    const int lane = threadIdx.x & 63;
    const float4* pr = (const float4*)(prototypes + (size_t)w * FEAT);
    float4 p0 = pr[lane], p1 = pr[lane + 64], p2 = pr[lane + 128], p3 = pr[lane + 192];

    const int cnt = (int)total[w];
    const int bs  = (int)base[w];
    const int iA = (cnt > 0) ? sorted_idx[bs] : 0;
    const int iB = (cnt > 1) ? sorted_idx[bs + 1] : 0;
    const float4* fA = (const float4*)(features + (size_t)iA * FEAT);
    float4 a0 = fA[lane], a1 = fA[lane + 64], a2 = fA[lane + 128], a3 = fA[lane + 192];
    const float4* fB = (const float4*)(features + (size_t)iB * FEAT);
    float4 b0 = fB[lane], b1 = fB[lane + 64], b2 = fB[lane + 128], b3 = fB[lane + 192];

    int k = 0;
    while (k + 2 <= cnt) {
        {
            const int iN = (k + 2 < cnt) ? sorted_idx[bs + k + 2] : 0;
            p0 = ema4(p0, a0); p1 = ema4(p1, a1); p2 = ema4(p2, a2); p3 = ema4(p3, a3);
            const float4* f = (const float4*)(features + (size_t)iN * FEAT);
            a0 = f[lane]; a1 = f[lane + 64]; a2 = f[lane + 128]; a3 = f[lane + 192];
            float ss = dot4(p0) + dot4(p1) + dot4(p2) + dot4(p3);
            #pragma unroll
            for (int o = 32; o; o >>= 1) ss += __shfl_xor(ss, o, 64);
            const float inv = 1.0f / fmaxf(sqrtf(ss), 1e-12f);
            p0 = scale4(p0, inv); p1 = scale4(p1, inv); p2 = scale4(p2, inv); p3 = scale4(p3, inv);
        }
        {
            const int iN = (k + 3 < cnt) ? sorted_idx[bs + k + 3] : 0;
            p0 = ema4(p0, b0); p1 = ema4(p1, b1); p2 = ema4(p2, b2); p3 = ema4(p3, b3);
            const float4* f = (const float4*)(features + (size_t)iN * FEAT);
            b0 = f[lane]; b1 = f[lane + 64]; b2 = f[lane + 128]; b3 = f[lane + 192];
            float ss = dot4(p0) + dot4(p1) + dot4(p2) + dot4(p3);
            #pragma unroll
            for (int o = 32; o; o >>= 1) ss += __shfl_xor(ss, o, 64);
            const float inv = 1.0f / fmaxf(sqrtf(ss), 1e-12f);
            p0 = scale4(p0, inv); p1 = scale4(p1, inv); p2 = scale4(p2, inv); p3 = scale4(p3, inv);
        }
        k += 2;
    }
    if (k < cnt) {
        p0 = ema4(p0, a0); p1 = ema4(p1, a1); p2 = ema4(p2, a2); p3 = ema4(p3, a3);
        float ss = dot4(p0) + dot4(p1) + dot4(p2) + dot4(p3);
        #pragma unroll
        for (int o = 32; o; o >>= 1) ss += __shfl_xor(ss, o, 64);
        const float inv = 1.0f / fmaxf(sqrtf(ss), 1e-12f);
        p0 = scale4(p0, inv); p1 = scale4(p1, inv); p2 = scale4(p2, inv); p3 = scale4(p3, inv);
    }
    float4* out = (float4*)(protos_new + (size_t)w * FEAT);
    out[lane] = p0; out[lane + 64] = p1; out[lane + 128] = p2; out[lane + 192] = p3;
}

// ---------------- bf16x3 split: A=[H|L|H], B=[H|H|L], rows padded to 1024 ----------------
__global__ __launch_bounds__(256) void convert_kernel(const float* __restrict__ P,
                                                      unsigned short* __restrict__ A,
                                                      unsigned short* __restrict__ Bm) {
    const int row = blockIdx.x;          // 0..1023
    const int t   = threadIdx.x;         // 256 threads x float4 = 1024 cols
    float4 v = make_float4(0.f, 0.f, 0.f, 0.f);
    if (row < N_CLS) v = *(const float4*)(P + (size_t)row * FEAT + 4 * t);
    ushort4 hi, lo;
    hi.x = f2bf(v.x); lo.x = f2bf(v.x - bf2f(hi.x));
    hi.y = f2bf(v.y); lo.y = f2bf(v.y - bf2f(hi.y));
    hi.z = f2bf(v.z); lo.z = f2bf(v.z - bf2f(hi.z));
    hi.w = f2bf(v.w); lo.w = f2bf(v.w - bf2f(hi.w));
    const size_t rb = (size_t)row * KCAT;
    *(ushort4*)(A  + rb +        4 * t) = hi;
    *(ushort4*)(A  + rb + 1024 + 4 * t) = lo;
    *(ushort4*)(A  + rb + 2048 + 4 * t) = hi;
    *(ushort4*)(Bm + rb +        4 * t) = hi;
    *(ushort4*)(Bm + rb + 1024 + 4 * t) = hi;
    *(ushort4*)(Bm + rb + 2048 + 4 * t) = lo;
}

// ---------------- MFMA gram (64x64 tile, BK=64) + fused exp row-sums ----------------
__global__ __launch_bounds__(256) void gram_kernel(const unsigned short* __restrict__ A,
                                                   const unsigned short* __restrict__ Bm,
                                                   float* __restrict__ S) {
    __shared__ short As[64 * LPITCH];
    __shared__ short Bs[64 * LPITCH];
    const int t = threadIdx.x;
    const int l = t & 63, wid = t >> 6;
    const int wr = wid >> 1, wc = wid & 1;
    const int m0 = blockIdx.y * 64, n0 = blockIdx.x * 64;
    const int lg = l >> 4, lc = l & 15;

    f32x4 acc[2][2] = {};

    const int r0s = t >> 3,          c0s = t & 7;           // chunk t
    const int r1s = (t + 256) >> 3,  c1s = t & 7;           // chunk t+256
    const short* Ag = (const short*)A;
    const short* Bg = (const short*)Bm;

    for (int k0 = 0; k0 < KCAT; k0 += GBK) {
        short8 a0 = *(const short8*)(Ag + (size_t)(m0 + r0s) * KCAT + k0 + c0s * 8);
        short8 a1 = *(const short8*)(Ag + (size_t)(m0 + r1s) * KCAT + k0 + c1s * 8);
        short8 g0 = *(const short8*)(Bg + (size_t)(n0 + r0s) * KCAT + k0 + c0s * 8);
        short8 g1 = *(const short8*)(Bg + (size_t)(n0 + r1s) * KCAT + k0 + c1s * 8);
        __syncthreads();                      // previous compute done before overwrite
        *(short8*)(As + r0s * LPITCH + c0s * 8) = a0;
        *(short8*)(As + r1s * LPITCH + c1s * 8) = a1;
        *(short8*)(Bs + r0s * LPITCH + c0s * 8) = g0;
        *(short8*)(Bs + r1s * LPITCH + c1s * 8) = g1;
        __syncthreads();
        #pragma unroll
        for (int kk = 0; kk < 2; ++kk) {
            short8 af[2], bf[2];
            #pragma unroll
            for (int mi = 0; mi < 2; ++mi)
                af[mi] = *(const short8*)(As + (wr * 32 + mi * 16 + lc) * LPITCH + kk * 32 + lg * 8);
            #pragma unroll
            for (int ni = 0; ni < 2; ++ni)
                bf[ni] = *(const short8*)(Bs + (wc * 32 + ni * 16 + lc) * LPITCH + kk * 32 + lg * 8);
            #pragma unroll
            for (int mi = 0; mi < 2; ++mi)
                #pragma unroll
                for (int ni = 0; ni < 2; ++ni)
                    acc[mi][ni] = __builtin_amdgcn_mfma_f32_16x16x32_bf16(af[mi], bf[ni], acc[mi][ni], 0, 0, 0);
        }
    }

    // epilogue: exp(10*logit) row sums, diagonal & padding excluded
    #pragma unroll
    for (int mi = 0; mi < 2; ++mi) {
        #pragma unroll
        for (int j = 0; j < 4; ++j) {
            const int gr = m0 + wr * 32 + mi * 16 + lg * 4 + j;
            float s = 0.f;
            #pragma unroll
            for (int ni = 0; ni < 2; ++ni) {
                const int gc = n0 + wc * 32 + ni * 16 + lc;
                if (gr < N_CLS && gc < N_CLS && gr != gc) s += expf(acc[mi][ni][j] * 10.0f);
            }
            #pragma unroll
            for (int m = 1; m < 16; m <<= 1) s += __shfl_xor(s, m, 64);
            if (lc == 0 && gr < N_CLS) atomicAdd(&S[gr], s);
        }
    }
}

// ---------------- final loss ----------------
__global__ __launch_bounds__(1024) void loss_kernel(const float* __restrict__ S,
                                                    float* __restrict__ out) {
    const int t = threadIdx.x;
    float v = 0.f;
    if (t < N_CLS) v = logf(S[t]) - logf(999.0f);
    #pragma unroll
    for (int off = 32; off; off >>= 1) v += __shfl_xor(v, off, 64);
    __shared__ float red[16];
    const int wv = t >> 6, lane = t & 63;
    if (lane == 0) red[wv] = v;
    __syncthreads();
    if (t < 16) {
        float s = red[t];
        #pragma unroll
        for (int off = 8; off; off >>= 1) s += __shfl_xor(s, off, 16);
        if (t == 0) out[0] = s / (float)N_CLS;   // TEMP/BASE_TEMP == 1.0
    }
}

extern "C" void kernel_launch(void* const* d_in, const int* in_sizes, int n_in,
                              void* d_out, int out_size, void* d_ws, size_t ws_size,
                              hipStream_t stream) {
    const float* features   = (const float*)d_in[0];
    const float* prototypes = (const float*)d_in[1];
    const int*   labels     = (const int*)d_in[2];
    float* out = (float*)d_out;

    char* ws = (char*)d_ws;
    unsigned*       hist   = (unsigned*)(ws);                 // 1000*128*4 = 512000
    unsigned*       base   = (unsigned*)(ws + 0x80000);       // 4 KB
    unsigned*       total  = (unsigned*)(ws + 0x81000);       // 4 KB
    int*            sorted = (int*)     (ws + 0x82000);       // 131072
    float*          S      = (float*)   (ws + 0xA4000);       // 4 KB
    float*          pnew   = (float*)   (ws + 0x100000);      // 4 MB
    unsigned short* Acat   = (unsigned short*)(ws + 0x500000);// 1024*3072*2 = 6 MB
    unsigned short* Bcat   = (unsigned short*)(ws + 0xB00000);// 6 MB

    hist_kernel   <<<NBLK_H, 256, 0, stream>>>(labels, hist);
    scan1_kernel  <<<250, 256, 0, stream>>>(hist, total);
    scan2_kernel  <<<1, 1024, 0, stream>>>(total, base);
    scatter_kernel<<<NBLK_H, 256, 0, stream>>>(labels, hist, base, sorted);
    hipMemsetAsync(S, 0, N_CLS * sizeof(float), stream);
    ema_kernel    <<<250, 256, 0, stream>>>(features, prototypes, sorted, base, total, pnew);
    convert_kernel<<<1024, 256, 0, stream>>>(pnew, Acat, Bcat);
    gram_kernel   <<<dim3(16, 16), 256, 0, stream>>>(Acat, Bcat, S);
    loss_kernel   <<<1, 1024, 0, stream>>>(S, out);
}

// Round 4
// 261.979 us; speedup vs baseline: 1.1402x; 1.0132x over previous
//
#include <hip/hip_runtime.h>
#include <hip/hip_bf16.h>
#include <math.h>

#define N_CLS 1000
#define FEAT  1024
#define BATCH 32768
#define NBLK_H 128
#define CHUNK  256
#define LPITCH 72
#define GRAM_BLOCKS 256

typedef short short8 __attribute__((ext_vector_type(8)));
typedef float f32x4  __attribute__((ext_vector_type(4)));

__device__ __forceinline__ unsigned short f2bf(float x) {
    union { __hip_bfloat16 h; unsigned short u; } cv;
    cv.h = __float2bfloat16(x);
    return cv.u;
}
__device__ __forceinline__ float bf2f(unsigned short u) {
    union { __hip_bfloat16 h; unsigned short u; } cv;
    cv.u = u;
    return __bfloat162float(cv.h);
}

// ---------------- counting-sort: histogram (transposed hist[l][b]) + zero S/counter ----------------
__global__ __launch_bounds__(256) void hist_kernel(const int* __restrict__ labels,
                                                   unsigned* __restrict__ hist,
                                                   float* __restrict__ S,
                                                   unsigned* __restrict__ counter) {
    __shared__ unsigned cnt[N_CLS];
    const int t = threadIdx.x, b = blockIdx.x;
    if (b == 0) {
        for (int i = t; i < N_CLS; i += 256) S[i] = 0.0f;
        if (t == 0) *counter = 0u;
    }
    for (int i = t; i < N_CLS; i += 256) cnt[i] = 0;
    __syncthreads();
    atomicAdd(&cnt[labels[b * CHUNK + t]], 1u);
    __syncthreads();
    for (int i = t; i < N_CLS; i += 256) hist[(size_t)i * NBLK_H + b] = cnt[i];
}

// ---------------- per-label wave scan over the 128 blocks ----------------
__global__ __launch_bounds__(256) void scan1_kernel(unsigned* __restrict__ hist,
                                                    unsigned* __restrict__ total) {
    const int l    = blockIdx.x * 4 + (threadIdx.x >> 6);
    const int lane = threadIdx.x & 63;
    unsigned v0 = hist[(size_t)l * NBLK_H + lane];
    unsigned v1 = hist[(size_t)l * NBLK_H + 64 + lane];
    unsigned x0 = v0, x1 = v1;
    #pragma unroll
    for (int off = 1; off < 64; off <<= 1) {
        unsigned u0 = __shfl_up(x0, off, 64);
        if (lane >= off) x0 += u0;
        unsigned u1 = __shfl_up(x1, off, 64);
        if (lane >= off) x1 += u1;
    }
    x1 += __shfl(x0, 63, 64);
    hist[(size_t)l * NBLK_H + lane]      = x0 - v0;   // exclusive prefix
    hist[(size_t)l * NBLK_H + 64 + lane] = x1 - v1;
    if (lane == 63) total[l] = x1;
}

// ---------------- exclusive scan of per-label totals ----------------
__global__ __launch_bounds__(1024) void scan2_kernel(const unsigned* __restrict__ total,
                                                     unsigned* __restrict__ base) {
    const int t = threadIdx.x;
    unsigned v = (t < N_CLS) ? total[t] : 0u;
    __shared__ unsigned sc[1024];
    sc[t] = v;
    __syncthreads();
    for (int off = 1; off < 1024; off <<= 1) {
        unsigned u = (t >= off) ? sc[t - off] : 0u;
        __syncthreads();
        sc[t] += u;
        __syncthreads();
    }
    if (t < N_CLS) base[t] = sc[t] - v;
}

// ---------------- counting-sort: stable scatter ----------------
__global__ __launch_bounds__(256) void scatter_kernel(const int* __restrict__ labels,
                                                      const unsigned* __restrict__ hist,
                                                      const unsigned* __restrict__ base,
                                                      int* __restrict__ sorted_idx) {
    __shared__ int lbl[CHUNK];
    __shared__ unsigned c[N_CLS];
    const int t = threadIdx.x, b = blockIdx.x;
    for (int i = t; i < N_CLS; i += 256) c[i] = 0;
    __syncthreads();
    const int i = b * CHUNK + t;
    const int l = labels[i];
    lbl[t] = l;
    atomicAdd(&c[l], 1u);
    __syncthreads();
    int rank = 0;
    if (c[l] > 1) {                       // only duplicated-in-block labels need ranking
        for (int j = 0; j < t; ++j) rank += (lbl[j] == l);
    }
    sorted_idx[base[l] + hist[(size_t)l * NBLK_H + b] + (unsigned)rank] = i;
}

// ---------------- EMA chains: one wave per label, 3-buffer prefetch, fused bf16 H/L write ----------------
__device__ __forceinline__ float4 ema4(float4 p, float4 f) {
    p.x = fmaf(0.95f, p.x, 0.05f * f.x);
    p.y = fmaf(0.95f, p.y, 0.05f * f.y);
    p.z = fmaf(0.95f, p.z, 0.05f * f.z);
    p.w = fmaf(0.95f, p.w, 0.05f * f.w);
    return p;
}
__device__ __forceinline__ float dot4(float4 a) {
    return a.x * a.x + a.y * a.y + a.z * a.z + a.w * a.w;
}
__device__ __forceinline__ float4 scale4(float4 a, float s) {
    a.x *= s; a.y *= s; a.z *= s; a.w *= s; return a;
}

__device__ __forceinline__ void ema_step(float4& p0, float4& p1, float4& p2, float4& p3,
                                         float4& x0, float4& x1, float4& x2, float4& x3,
                                         const float* __restrict__ features, int iN, int lane) {
    p0 = ema4(p0, x0); p1 = ema4(p1, x1); p2 = ema4(p2, x2); p3 = ema4(p3, x3);
    const float4* f = (const float4*)(features + (size_t)iN * FEAT);   // prefetch next
    x0 = f[lane]; x1 = f[lane + 64]; x2 = f[lane + 128]; x3 = f[lane + 192];
    float ss = dot4(p0) + dot4(p1) + dot4(p2) + dot4(p3);
    #pragma unroll
    for (int o = 32; o; o >>= 1) ss += __shfl_xor(ss, o, 64);
    const float inv = 1.0f / fmaxf(sqrtf(ss), 1e-12f);
    p0 = scale4(p0, inv); p1 = scale4(p1, inv); p2 = scale4(p2, inv); p3 = scale4(p3, inv);
}

__device__ __forceinline__ void write_hl(unsigned short* __restrict__ H,
                                         unsigned short* __restrict__ L,
                                         size_t off, float4 v) {
    ushort4 hi, lo;
    hi.x = f2bf(v.x); lo.x = f2bf(v.x - bf2f(hi.x));
    hi.y = f2bf(v.y); lo.y = f2bf(v.y - bf2f(hi.y));
    hi.z = f2bf(v.z); lo.z = f2bf(v.z - bf2f(hi.z));
    hi.w = f2bf(v.w); lo.w = f2bf(v.w - bf2f(hi.w));
    *(ushort4*)(H + off) = hi;
    *(ushort4*)(L + off) = lo;
}

__global__ __launch_bounds__(256) void ema_kernel(const float* __restrict__ features,
                                                  const float* __restrict__ prototypes,
                                                  const int* __restrict__ sorted_idx,
                                                  const unsigned* __restrict__ base,
                                                  const unsigned* __restrict__ total,
                                                  unsigned short* __restrict__ Hg,
                                                  unsigned short* __restrict__ Lg) {
    const int w    = blockIdx.x * 4 + (threadIdx.x >> 6);
    const int lane = threadIdx.x & 63;
    const float4* pr = (const float4*)(prototypes + (size_t)w * FEAT);
    float4 p0 = pr[lane], p1 = pr[lane + 64], p2 = pr[lane + 128], p3 = pr[lane + 192];

    const int cnt = (int)total[w];
    const int bs  = (int)base[w];
    int myidx = (lane < cnt) ? sorted_idx[bs + lane] : 0;   // whole chain in one load (cnt<=64 w.h.p.)

    #define GETIDX(K) (((K) < cnt) ? (((K) < 64) ? __shfl(myidx, (K), 64) : sorted_idx[bs + (K)]) : 0)

    const int iA = GETIDX(0), iB = GETIDX(1), iC = GETIDX(2);
    const float4* fA = (const float4*)(features + (size_t)iA * FEAT);
    float4 a0 = fA[lane], a1 = fA[lane + 64], a2 = fA[lane + 128], a3 = fA[lane + 192];
    const float4* fB = (const float4*)(features + (size_t)iB * FEAT);
    float4 b0 = fB[lane], b1 = fB[lane + 64], b2 = fB[lane + 128], b3 = fB[lane + 192];
    const float4* fC = (const float4*)(features + (size_t)iC * FEAT);
    float4 c0 = fC[lane], c1 = fC[lane + 64], c2 = fC[lane + 128], c3 = fC[lane + 192];

    int k = 0;
    while (k + 3 <= cnt) {
        ema_step(p0,p1,p2,p3, a0,a1,a2,a3, features, GETIDX(k + 3), lane); ++k;
        ema_step(p0,p1,p2,p3, b0,b1,b2,b3, features, GETIDX(k + 3), lane); ++k;
        ema_step(p0,p1,p2,p3, c0,c1,c2,c3, features, GETIDX(k + 3), lane); ++k;
    }
    if (k < cnt) { ema_step(p0,p1,p2,p3, a0,a1,a2,a3, features, 0, lane); ++k; }
    if (k < cnt) { ema_step(p0,p1,p2,p3, b0,b1,b2,b3, features, 0, lane); ++k; }

    const size_t rb = (size_t)w * FEAT;
    write_hl(Hg, Lg, rb +       4 * lane, p0);
    write_hl(Hg, Lg, rb + 256 + 4 * lane, p1);
    write_hl(Hg, Lg, rb + 512 + 4 * lane, p2);
    write_hl(Hg, Lg, rb + 768 + 4 * lane, p3);
    #undef GETIDX
}

// ---------------- MFMA gram: C = H·H^T + L·H^T + H·L^T, fused exp row-sums + loss ----------------
__global__ __launch_bounds__(256) void gram_kernel(const unsigned short* __restrict__ Hg,
                                                   const unsigned short* __restrict__ Lg,
                                                   float* __restrict__ S,
                                                   unsigned* __restrict__ counter,
                                                   float* __restrict__ out) {
    __shared__ short Hms[64 * LPITCH];
    __shared__ short Lms[64 * LPITCH];
    __shared__ short Hns[64 * LPITCH];
    __shared__ short Lns[64 * LPITCH];
    const int t = threadIdx.x;
    const int l = t & 63, wid = t >> 6;
    const int wr = wid >> 1, wc = wid & 1;
    const int m0 = blockIdx.y * 64, n0 = blockIdx.x * 64;
    const int lg = l >> 4, lc = l & 15;

    const short* Hp = (const short*)Hg;
    const short* Lp = (const short*)Lg;

    f32x4 acc[2][2] = {};

    const int r0 = t >> 3,           c0 = t & 7;            // staging unit t
    const int r1 = (t + 256) >> 3,   c1 = t & 7;            // staging unit t+256

    for (int k0 = 0; k0 < FEAT; k0 += 64) {
        short8 hm0 = *(const short8*)(Hp + (size_t)(m0 + r0) * FEAT + k0 + c0 * 8);
        short8 hm1 = *(const short8*)(Hp + (size_t)(m0 + r1) * FEAT + k0 + c1 * 8);
        short8 lm0 = *(const short8*)(Lp + (size_t)(m0 + r0) * FEAT + k0 + c0 * 8);
        short8 lm1 = *(const short8*)(Lp + (size_t)(m0 + r1) * FEAT + k0 + c1 * 8);
        short8 hn0 = *(const short8*)(Hp + (size_t)(n0 + r0) * FEAT + k0 + c0 * 8);
        short8 hn1 = *(const short8*)(Hp + (size_t)(n0 + r1) * FEAT + k0 + c1 * 8);
        short8 ln0 = *(const short8*)(Lp + (size_t)(n0 + r0) * FEAT + k0 + c0 * 8);
        short8 ln1 = *(const short8*)(Lp + (size_t)(n0 + r1) * FEAT + k0 + c1 * 8);
        __syncthreads();                       // previous compute done before overwrite
        *(short8*)(Hms + r0 * LPITCH + c0 * 8) = hm0;
        *(short8*)(Hms + r1 * LPITCH + c1 * 8) = hm1;
        *(short8*)(Lms + r0 * LPITCH + c0 * 8) = lm0;
        *(short8*)(Lms + r1 * LPITCH + c1 * 8) = lm1;
        *(short8*)(Hns + r0 * LPITCH + c0 * 8) = hn0;
        *(short8*)(Hns + r1 * LPITCH + c1 * 8) = hn1;
        *(short8*)(Lns + r0 * LPITCH + c0 * 8) = ln0;
        *(short8*)(Lns + r1 * LPITCH + c1 * 8) = ln1;
        __syncthreads();
        #pragma unroll
        for (int kk = 0; kk < 2; ++kk) {
            short8 ah[2], al[2], bh[2], bl[2];
            #pragma unroll
            for (int mi = 0; mi < 2; ++mi) {
                ah[mi] = *(const short8*)(Hms + (wr * 32 + mi * 16 + lc) * LPITCH + kk * 32 + lg * 8);
                al[mi] = *(const short8*)(Lms + (wr * 32 + mi * 16 + lc) * LPITCH + kk * 32 + lg * 8);
            }
            #pragma unroll
            for (int ni = 0; ni < 2; ++ni) {
                bh[ni] = *(const short8*)(Hns + (wc * 32 + ni * 16 + lc) * LPITCH + kk * 32 + lg * 8);
                bl[ni] = *(const short8*)(Lns + (wc * 32 + ni * 16 + lc) * LPITCH + kk * 32 + lg * 8);
            }
            #pragma unroll
            for (int mi = 0; mi < 2; ++mi)
                #pragma unroll
                for (int ni = 0; ni < 2; ++ni) {
                    acc[mi][ni] = __builtin_amdgcn_mfma_f32_16x16x32_bf16(ah[mi], bh[ni], acc[mi][ni], 0, 0, 0);
                    acc[mi][ni] = __builtin_amdgcn_mfma_f32_16x16x32_bf16(al[mi], bh[ni], acc[mi][ni], 0, 0, 0);
                    acc[mi][ni] = __builtin_amdgcn_mfma_f32_16x16x32_bf16(ah[mi], bl[ni], acc[mi][ni], 0, 0, 0);
                }
        }
    }

    // epilogue: exp(10*logit) row sums, diagonal & out-of-range excluded
    #pragma unroll
    for (int mi = 0; mi < 2; ++mi) {
        #pragma unroll
        for (int j = 0; j < 4; ++j) {
            const int gr = m0 + wr * 32 + mi * 16 + lg * 4 + j;
            float s = 0.f;
            #pragma unroll
            for (int ni = 0; ni < 2; ++ni) {
                const int gc = n0 + wc * 32 + ni * 16 + lc;
                if (gr < N_CLS && gc < N_CLS && gr != gc) s += expf(acc[mi][ni][j] * 10.0f);
            }
            #pragma unroll
            for (int m = 1; m < 16; m <<= 1) s += __shfl_xor(s, m, 64);
            if (lc == 0 && gr < N_CLS) atomicAdd(&S[gr], s);
        }
    }

    // fused loss: last block reduces S
    __threadfence();
    __shared__ int amlast;
    if (t == 0) {
        unsigned old = __hip_atomic_fetch_add(counter, 1u, __ATOMIC_ACQ_REL, __HIP_MEMORY_SCOPE_AGENT);
        amlast = (old == GRAM_BLOCKS - 1) ? 1 : 0;
    }
    __syncthreads();
    if (amlast) {
        float a = 0.f;
        for (int i = t; i < N_CLS; i += 256) {
            float sv = __hip_atomic_load(&S[i], __ATOMIC_RELAXED, __HIP_MEMORY_SCOPE_AGENT);
            a += logf(sv);
        }
        #pragma unroll
        for (int o = 32; o; o >>= 1) a += __shfl_xor(a, o, 64);
        __shared__ float red[4];
        if (l == 0) red[wid] = a;
        __syncthreads();
        if (t == 0) {
            float tot = red[0] + red[1] + red[2] + red[3];
            out[0] = tot / (float)N_CLS - logf(999.0f);   // TEMP/BASE_TEMP == 1.0
        }
    }
}

extern "C" void kernel_launch(void* const* d_in, const int* in_sizes, int n_in,
                              void* d_out, int out_size, void* d_ws, size_t ws_size,
                              hipStream_t stream) {
    const float* features   = (const float*)d_in[0];
    const float* prototypes = (const float*)d_in[1];
    const int*   labels     = (const int*)d_in[2];
    float* out = (float*)d_out;

    char* ws = (char*)d_ws;
    unsigned*       hist    = (unsigned*)(ws);                 // 1000*128*4 = 512000
    unsigned*       base    = (unsigned*)(ws + 0x80000);       // 4 KB
    unsigned*       total   = (unsigned*)(ws + 0x81000);       // 4 KB
    int*            sorted  = (int*)     (ws + 0x82000);       // 131072
    float*          S       = (float*)   (ws + 0xA4000);       // 4 KB
    unsigned*       counter = (unsigned*)(ws + 0xA5000);       // 4 B
    unsigned short* Hg      = (unsigned short*)(ws + 0x100000);// 1024*1024*2 = 2 MB
    unsigned short* Lg      = (unsigned short*)(ws + 0x300000);// 2 MB

    hist_kernel   <<<NBLK_H, 256, 0, stream>>>(labels, hist, S, counter);
    scan1_kernel  <<<250, 256, 0, stream>>>(hist, total);
    scan2_kernel  <<<1, 1024, 0, stream>>>(total, base);
    scatter_kernel<<<NBLK_H, 256, 0, stream>>>(labels, hist, base, sorted);
    ema_kernel    <<<250, 256, 0, stream>>>(features, prototypes, sorted, base, total, Hg, Lg);
    gram_kernel   <<<dim3(16, 16), 256, 0, stream>>>(Hg, Lg, S, counter, out);
}